// Round 1
// baseline (941.639 us; speedup 1.0000x reference)
//
#include <hip/hip_runtime.h>

using short8 = __attribute__((ext_vector_type(8))) short;
using f32x16 = __attribute__((ext_vector_type(16))) float;

#define THR_LOGIT (-1.0986122886681098f)   // ln(1/3): sigmoid(x)>0.25 <=> x>ln(1/3)

__device__ __forceinline__ unsigned short f2bf(float f) {
  unsigned u = __float_as_uint(f);
  u = (u + 0x7FFFu + ((u >> 16) & 1u)) >> 16;   // RNE
  return (unsigned short)u;
}

// ---------------- prep: weight transposes ----------------
// wt2[tap][ch][c] bf16  (27*32*128)  <- conv1_w[ch][c][tap]
// w1t[c][j]  f32 (128*128)           <- proj_w1[j][c]
// w2t[j][d]  f32 (128*64)            <- proj_w2[d][j]
__global__ void __launch_bounds__(256) k_prep(const float* __restrict__ c1w,
    const float* __restrict__ pw1, const float* __restrict__ pw2,
    short* __restrict__ wt2, float* __restrict__ w1t, float* __restrict__ w2t) {
  int i = blockIdx.x * 256 + threadIdx.x;
  if (i < 110592) {
    int tap = i >> 12; int rem = i & 4095; int ch = rem >> 7; int c = rem & 127;
    wt2[i] = (short)f2bf(c1w[ch * 3456 + c * 27 + tap]);
  } else if (i < 126976) {
    int i2 = i - 110592; int c = i2 >> 7; int j = i2 & 127;
    w1t[i2] = pw1[j * 128 + c];
  } else if (i < 135168) {
    int i3 = i - 126976; int j = i3 >> 6; int d = i3 & 63;
    w2t[i3] = pw2[d * 128 + j];
  }
}

// inv[pos] = s if voxel_idx[s]==pos else -1
__global__ void k_inv(const int* __restrict__ vidx, int* __restrict__ inv) {
  int t = threadIdx.x;
  for (int k = t; k < 4096; k += 256) inv[k] = -1;
  __syncthreads();
  if (t < 100) inv[vidx[t]] = t;
}

// ---------------- stage: transpose->bf16 NDHWC, patch partial sums, voxel gather ----
// grid 512: b(2) x z(64) x yp(4); each block loops 16 y rows.
// S4[b][z][yp][c][xp] = sum over 16y x 16x
// X rows: vec rows written later by k_vecreduce; vox rows written here.
__global__ void __launch_bounds__(256) k_stage(const float* __restrict__ src,
    short* __restrict__ in2, float* __restrict__ S4, float* __restrict__ Xmat,
    const int* __restrict__ inv, int vox_row_base) {
  __shared__ float tile[128][65];
  __shared__ int mcnt;
  __shared__ int mx[64];
  __shared__ int mrow[64];
  int bi = blockIdx.x;
  int b = bi >> 8, z = (bi >> 2) & 63, yp = bi & 3;
  int t = threadIdx.x;
  int zp = z >> 4, pz = z & 15;
  int cc = t & 127, xh = t >> 7;
  float part0 = 0.f, part1 = 0.f;

  for (int y0 = 0; y0 < 16; ++y0) {
    int y = yp * 16 + y0;
    __syncthreads();
    if (t == 0) mcnt = 0;
    // load tile[c][x] (coalesced 256B rows)
    {
      int x = t & 63, w = t >> 6;
      const float* sp = src + (long)b * 128 * 262144 + (long)z * 4096 + (long)y * 64 + x;
      #pragma unroll 4
      for (int it = 0; it < 32; ++it) {
        int c = it * 4 + w;
        tile[c][x] = sp[(long)c * 262144];
      }
    }
    __syncthreads();
    // write bf16 NDHWC (anchor only)
    if (in2 != nullptr) {
      #pragma unroll
      for (int it = 0; it < 4; ++it) {
        int chunk = it * 256 + t;
        int x = chunk >> 4, c8 = chunk & 15;
        short8 pk;
        #pragma unroll
        for (int j = 0; j < 8; ++j) pk[j] = (short)f2bf(tile[c8 * 8 + j][x]);
        *(short8*)(in2 + ((((long)(b * 64 + z) * 64 + y) * 64 + x) * 128 + c8 * 8)) = pk;
      }
    }
    // patch partial sums: thread (c = t&127, xh = t>>7) handles xp = xh*2+{0,1}
    {
      float s0 = 0.f, s1 = 0.f;
      #pragma unroll
      for (int px = 0; px < 16; ++px) s0 += tile[cc][(xh * 2) * 16 + px];
      #pragma unroll
      for (int px = 0; px < 16; ++px) s1 += tile[cc][(xh * 2 + 1) * 16 + px];
      part0 += s0; part1 += s1;
    }
    // gather detect: local pos uses (pz, py=y0, px=x&15)
    if (t < 64) {
      int s = inv[pz * 256 + y0 * 16 + (t & 15)];
      if (s >= 0) {
        int idx = atomicAdd(&mcnt, 1);
        mx[idx] = t;
        int n = zp * 16 + yp * 4 + (t >> 4);
        mrow[idx] = vox_row_base + (b * 64 + n) * 100 + s;
      }
    }
    __syncthreads();
    int mc = mcnt;
    for (int i = 0; i < mc; ++i) {
      if (t < 128) Xmat[(long)mrow[i] * 128 + t] = tile[t][mx[i]];
    }
  }
  long sb = ((long)(b * 64 + z) * 4 + yp) * 512;
  S4[sb + cc * 4 + xh * 2 + 0] = part0;
  S4[sb + cc * 4 + xh * 2 + 1] = part1;
}

// ---------------- conv: bf16 MFMA, fused relu/1x1/sigmoid-threshold/patch-count ----
// grid 1024: b(2) x zg(32, 2 z each) x yg(16, 4 y each: one per wave)
__global__ void __launch_bounds__(256) k_conv(const short* __restrict__ in2,
    const short* __restrict__ wt2, const float* __restrict__ c1b,
    const float* __restrict__ c2w, const float* __restrict__ c2b,
    int* __restrict__ counts) {
  int bi = blockIdx.x;
  int b = bi >> 9, zg = (bi >> 4) & 31, yg = bi & 15;
  int tid = threadIdx.x;
  int lane = tid & 63;
  int l31 = lane & 31, half = lane >> 5;
  int y = yg * 4 + (tid >> 6);
  float b1v = c1b[l31];
  float w2v = c2w[l31];
  float b2v = c2b[0];
  int cnt[4] = {0, 0, 0, 0};
  const short8 zer = {};

  for (int iz = 0; iz < 2; ++iz) {
    int z = zg * 2 + iz;
    f32x16 acc0 = {}, acc1 = {};
    for (int tap = 0; tap < 27; ++tap) {
      int dz = tap / 9 - 1;
      int r9 = tap - (tap / 9) * 9;
      int dy = r9 / 3 - 1;
      int dx = (r9 - (r9 / 3) * 3) - 1;
      int zz = z + dz, yy = y + dy;
      if (((unsigned)zz >= 64u) || ((unsigned)yy >= 64u)) continue;
      int xa = l31 + dx, xb = xa + 32;
      bool va = (unsigned)xa < 64u, vb = (unsigned)xb < 64u;
      int xac = max(min(xa, 63), 0), xbc = max(min(xb, 63), 0);
      long rowb = ((long)((b * 64 + zz) * 64 + yy)) * 64;
      const short8* pA0 = (const short8*)(in2 + (rowb + xac) * 128 + half * 8);
      const short8* pA1 = (const short8*)(in2 + (rowb + xbc) * 128 + half * 8);
      const short8* pB  = (const short8*)(wt2 + (((long)tap * 32 + l31) * 128 + half * 8));
      #pragma unroll
      for (int ks = 0; ks < 8; ++ks) {
        short8 wfr = pB[ks * 2];
        short8 a0 = pA0[ks * 2];
        short8 a1 = pA1[ks * 2];
        a0 = va ? a0 : zer;
        a1 = vb ? a1 : zer;
        acc0 = __builtin_amdgcn_mfma_f32_32x32x16_bf16(a0, wfr, acc0, 0, 0, 0);
        acc1 = __builtin_amdgcn_mfma_f32_32x32x16_bf16(a1, wfr, acc1, 0, 0, 0);
      }
    }
    // epilogue: logit per x, threshold, per-xp count
    // C/D map (m74/m101): ch = lane&31, row = (r&3) + 8*(r>>2) + 4*half; x = m*32+row
    #pragma unroll
    for (int r = 0; r < 16; ++r) {
      float v0 = fmaxf(acc0[r] + b1v, 0.f) * w2v;
      float v1 = fmaxf(acc1[r] + b1v, 0.f) * w2v;
      v0 += __shfl_xor(v0, 1);  v1 += __shfl_xor(v1, 1);
      v0 += __shfl_xor(v0, 2);  v1 += __shfl_xor(v1, 2);
      v0 += __shfl_xor(v0, 4);  v1 += __shfl_xor(v1, 4);
      v0 += __shfl_xor(v0, 8);  v1 += __shfl_xor(v1, 8);
      v0 += __shfl_xor(v0, 16); v1 += __shfl_xor(v1, 16);
      int bit0 = (v0 + b2v) > THR_LOGIT;
      int bit1 = (v1 + b2v) > THR_LOGIT;
      int hi = r >> 3;                 // row>=16 <=> r>=8
      cnt[hi] += bit0;                 // m=0 -> xp 0/1
      cnt[2 + hi] += bit1;             // m=1 -> xp 2/3
    }
  }
  __shared__ int lcnt[4];
  if (tid < 4) lcnt[tid] = 0;
  __syncthreads();
  if (l31 == 0) {                      // lanes 0 and 32 each hold their half's exact count
    atomicAdd(&lcnt[0], cnt[0]); atomicAdd(&lcnt[1], cnt[1]);
    atomicAdd(&lcnt[2], cnt[2]); atomicAdd(&lcnt[3], cnt[3]);
  }
  __syncthreads();
  if (tid < 4) {
    int n = (zg >> 3) * 16 + (yg >> 2) * 4 + tid;
    atomicAdd(&counts[b * 64 + n], lcnt[tid]);
  }
}

// ---------------- reduce S4 -> X vec rows (deterministic) ----------------
__global__ void __launch_bounds__(256) k_vecreduce(const float* __restrict__ S4a,
    const float* __restrict__ S4p, float* __restrict__ Xmat) {
  int g = blockIdx.x * 256 + threadIdx.x;   // 32768
  int ten = g >> 14, rem = g & 16383;
  int b = rem >> 13, n = (rem >> 7) & 63, c = rem & 127;
  int zp = n >> 4, yp = (n >> 2) & 3, xp = n & 3;
  const float* S = ten ? S4p : S4a;
  float s = 0.f;
  #pragma unroll
  for (int k = 0; k < 16; ++k)
    s += S[((long)(b * 64 + zp * 16 + k) * 4 + yp) * 512 + c * 4 + xp];
  Xmat[(long)(ten * 128 + b * 64 + n) * 128 + c] = s * (1.f / 4096.f);
}

// ---------------- projector MLP + normalize ----------------
// 16 rows per block; 1616 blocks.
__global__ void __launch_bounds__(256) k_proj(const float* __restrict__ Xmat,
    const float* __restrict__ w1t, const float* __restrict__ pb1,
    const float* __restrict__ w2t, const float* __restrict__ pb2,
    float* __restrict__ P) {
  __shared__ float xsT[128][20];   // [c][r]
  __shared__ float hsT[128][20];   // [j][r]
  __shared__ float os[16][68];     // [r][d]
  int bi = blockIdx.x;
  long row0 = (long)bi * 16;
  int t = threadIdx.x;
  {
    int r = t >> 4, c0 = (t & 15) * 8;
    const float* xp = Xmat + (row0 + r) * 128 + c0;
    #pragma unroll
    for (int k = 0; k < 8; ++k) xsT[c0 + k][r] = xp[k];
  }
  __syncthreads();
  {
    int j = t & 127, rh = t >> 7;
    float hacc[8];
    float bb = pb1[j];
    #pragma unroll
    for (int r8 = 0; r8 < 8; ++r8) hacc[r8] = bb;
    for (int c = 0; c < 128; ++c) {
      float w = w1t[c * 128 + j];
      float4 xlo = *(const float4*)&xsT[c][rh * 8];
      float4 xhi = *(const float4*)&xsT[c][rh * 8 + 4];
      hacc[0] += xlo.x * w; hacc[1] += xlo.y * w; hacc[2] += xlo.z * w; hacc[3] += xlo.w * w;
      hacc[4] += xhi.x * w; hacc[5] += xhi.y * w; hacc[6] += xhi.z * w; hacc[7] += xhi.w * w;
    }
    #pragma unroll
    for (int r8 = 0; r8 < 8; ++r8) hsT[j][rh * 8 + r8] = fmaxf(hacc[r8], 0.f);
  }
  __syncthreads();
  {
    int d = t & 63, rq = t >> 6;
    float oacc[4];
    float bb = pb2[d];
    #pragma unroll
    for (int r4 = 0; r4 < 4; ++r4) oacc[r4] = bb;
    for (int j = 0; j < 128; ++j) {
      float w = w2t[j * 64 + d];
      float4 hv = *(const float4*)&hsT[j][rq * 4];
      oacc[0] += hv.x * w; oacc[1] += hv.y * w; oacc[2] += hv.z * w; oacc[3] += hv.w * w;
    }
    #pragma unroll
    for (int r4 = 0; r4 < 4; ++r4) os[rq * 4 + r4][d] = oacc[r4];
  }
  __syncthreads();
  {
    int r = t >> 4, dg = t & 15;
    float4 v = *(const float4*)&os[r][dg * 4];
    float ss = v.x * v.x + v.y * v.y + v.z * v.z + v.w * v.w;
    ss += __shfl_xor(ss, 1); ss += __shfl_xor(ss, 2);
    ss += __shfl_xor(ss, 4); ss += __shfl_xor(ss, 8);
    float sc = 1.f / fmaxf(sqrtf(ss), 1e-12f);
    float4 o; o.x = v.x * sc; o.y = v.y * sc; o.z = v.z * sc; o.w = v.w * sc;
    *(float4*)&P[(row0 + r) * 64 + dg * 4] = o;
  }
}

// ---------------- sim + logsumexp per (b,n) ----------------
__global__ void __launch_bounds__(128) k_sim(const float* __restrict__ P,
                                             float* __restrict__ vloss) {
  __shared__ float ps[100][68];
  __shared__ float red[128];
  int bn = blockIdx.x;
  int t = threadIdx.x;
  long pbase = (long)(13056 + bn * 100) * 64;
  for (int i = t; i < 1600; i += 128) {
    int r = i >> 4, dg = i & 15;
    *(float4*)&ps[r][dg * 4] = *(const float4*)&P[pbase + r * 64 + dg * 4];
  }
  float4 areg[16];
  long abase = (long)(256 + bn * 100) * 64;
  if (t < 100) {
    #pragma unroll
    for (int j = 0; j < 16; ++j) areg[j] = *(const float4*)&P[abase + (long)t * 64 + j * 4];
  }
  __syncthreads();
  float res = 0.f;
  if (t < 100) {
    float m = -1e30f, sum = 0.f, diag = 0.f;
    for (int t2 = 0; t2 < 100; ++t2) {
      float d = 0.f;
      #pragma unroll
      for (int j = 0; j < 16; ++j) {
        float4 pv = *(const float4*)&ps[t2][j * 4];
        d += areg[j].x * pv.x + areg[j].y * pv.y + areg[j].z * pv.z + areg[j].w * pv.w;
      }
      float sim = d * 10.f;
      if (t2 == t) diag = sim;
      float nm = fmaxf(m, sim);
      sum = sum * __expf(m - nm) + __expf(sim - nm);
      m = nm;
    }
    res = m + logf(sum) - diag;
  }
  red[t] = res;
  __syncthreads();
  if (t == 0) {
    float s = 0.f;
    for (int i = 0; i < 100; ++i) s += red[i];
    vloss[bn] = s * 0.01f;
  }
}

// ---------------- final weighted reduction ----------------
__global__ void __launch_bounds__(128) k_final(const float* __restrict__ P,
    const float* __restrict__ vloss, const int* __restrict__ counts,
    const float* __restrict__ lw, float* __restrict__ out) {
  int t = threadIdx.x;
  int lane = t & 63;
  float pterm = 0.f, vterm = 0.f; int vcnt = 0;
  {
    int c = counts[t];
    bool maskv = c >= 2458;   // ratio > 0.6
    bool maskp = c <= 1638;   // ratio < 0.4
    float d = 0.f;
    for (int k = 0; k < 64; ++k) d += P[t * 64 + k] * P[(128 + t) * 64 + k];
    if (maskp) { pterm = -d * 10.f; vcnt += 1; }
    if (maskv) { vterm = vloss[t];  vcnt += 1; }
  }
  for (int m = 1; m < 64; m <<= 1) {
    pterm += __shfl_xor(pterm, m);
    vterm += __shfl_xor(vterm, m);
    vcnt  += __shfl_xor(vcnt, m);
  }
  __shared__ float sp[2], sv[2]; __shared__ int sc[2];
  if (lane == 0) { sp[t >> 6] = pterm; sv[t >> 6] = vterm; sc[t >> 6] = vcnt; }
  __syncthreads();
  if (t == 0) {
    float psum = sp[0] + sp[1], vsum = sv[0] + sv[1];
    int vc = sc[0] + sc[1];
    float total = lw[0] * psum + lw[1] * vsum;
    out[0] = (vc > 0) ? total / (float)vc : 0.f;
  }
}

// ---------------- launch ----------------
extern "C" void kernel_launch(void* const* d_in, const int* in_sizes, int n_in,
                              void* d_out, int out_size, void* d_ws, size_t ws_size,
                              hipStream_t stream) {
  const float* anchor   = (const float*)d_in[0];
  const float* positive = (const float*)d_in[1];
  const float* c1w = (const float*)d_in[2];
  const float* c1b = (const float*)d_in[3];
  const float* c2w = (const float*)d_in[4];
  const float* c2b = (const float*)d_in[5];
  const float* pw1 = (const float*)d_in[6];
  const float* pb1 = (const float*)d_in[7];
  const float* pw2 = (const float*)d_in[8];
  const float* pb2 = (const float*)d_in[9];
  const float* lw  = (const float*)d_in[10];
  const int*   vidx = (const int*)d_in[11];

  char* ws = (char*)d_ws;
  short* in2   = (short*)(ws + 0);                 // 134,217,728
  float* S4a   = (float*)(ws + 134217728);         // 1,048,576
  float* S4p   = (float*)(ws + 135266304);         // 1,048,576
  float* X     = (float*)(ws + 136314880);         // 13,238,272
  float* P     = (float*)(ws + 149553152);         // 6,619,136
  short* wt2   = (short*)(ws + 156172288);         // 221,184
  float* w1t   = (float*)(ws + 156393472);         // 65,536
  float* w2t   = (float*)(ws + 156459008);         // 32,768
  int*   inv   = (int*)  (ws + 156491776);         // 16,384
  int*   counts= (int*)  (ws + 156508160);         // 512
  float* vloss = (float*)(ws + 156508672);         // 512

  hipMemsetAsync(counts, 0, 128 * sizeof(int), stream);
  k_prep<<<528, 256, 0, stream>>>(c1w, pw1, pw2, wt2, w1t, w2t);
  k_inv<<<1, 256, 0, stream>>>(vidx, inv);
  k_stage<<<512, 256, 0, stream>>>(anchor,   in2,     S4a, X, inv, 256);
  k_stage<<<512, 256, 0, stream>>>(positive, nullptr, S4p, X, inv, 13056);
  k_conv<<<1024, 256, 0, stream>>>(in2, wt2, c1b, c2w, c2b, counts);
  k_vecreduce<<<128, 256, 0, stream>>>(S4a, S4p, X);
  k_proj<<<1616, 256, 0, stream>>>(X, w1t, pb1, w2t, pb2, P);
  k_sim<<<128, 128, 0, stream>>>(P, vloss);
  k_final<<<1, 128, 0, stream>>>(P, vloss, counts, lw, (float*)d_out);
}

// Round 2
// 732.691 us; speedup vs baseline: 1.2852x; 1.2852x over previous
//
#include <hip/hip_runtime.h>

using short8 = __attribute__((ext_vector_type(8))) short;
using f32x16 = __attribute__((ext_vector_type(16))) float;

#define THR_LOGIT (-1.0986122886681098f)   // ln(1/3): sigmoid(x)>0.25 <=> x>ln(1/3)

__device__ __forceinline__ unsigned short f2bf(float f) {
  unsigned u = __float_as_uint(f);
  u = (u + 0x7FFFu + ((u >> 16) & 1u)) >> 16;   // RNE
  return (unsigned short)u;
}

// ---------------- prep: weight transposes ----------------
__global__ void __launch_bounds__(256) k_prep(const float* __restrict__ c1w,
    const float* __restrict__ pw1, const float* __restrict__ pw2,
    short* __restrict__ wt2, float* __restrict__ w1t, float* __restrict__ w2t) {
  int i = blockIdx.x * 256 + threadIdx.x;
  if (i < 110592) {
    int tap = i >> 12; int rem = i & 4095; int ch = rem >> 7; int c = rem & 127;
    wt2[i] = (short)f2bf(c1w[ch * 3456 + c * 27 + tap]);
  } else if (i < 126976) {
    int i2 = i - 110592; int c = i2 >> 7; int j = i2 & 127;
    w1t[i2] = pw1[j * 128 + c];
  } else if (i < 135168) {
    int i3 = i - 126976; int j = i3 >> 6; int d = i3 & 63;
    w2t[i3] = pw2[d * 128 + j];
  }
}

__global__ void k_inv(const int* __restrict__ vidx, int* __restrict__ inv) {
  int t = threadIdx.x;
  for (int k = t; k < 4096; k += 256) inv[k] = -1;
  __syncthreads();
  if (t < 100) inv[vidx[t]] = t;
}

// ---------------- stage: transpose->bf16 NDHWC, patch partial sums, voxel gather ----
__global__ void __launch_bounds__(256) k_stage(const float* __restrict__ src,
    short* __restrict__ in2, float* __restrict__ S4, float* __restrict__ Xmat,
    const int* __restrict__ inv, int vox_row_base) {
  __shared__ float tile[128][65];
  __shared__ int mcnt;
  __shared__ int mx[64];
  __shared__ int mrow[64];
  int bi = blockIdx.x;
  int b = bi >> 8, z = (bi >> 2) & 63, yp = bi & 3;
  int t = threadIdx.x;
  int zp = z >> 4, pz = z & 15;
  int cc = t & 127, xh = t >> 7;
  float part0 = 0.f, part1 = 0.f;

  for (int y0 = 0; y0 < 16; ++y0) {
    int y = yp * 16 + y0;
    __syncthreads();
    if (t == 0) mcnt = 0;
    {
      int x = t & 63, w = t >> 6;
      const float* sp = src + (long)b * 128 * 262144 + (long)z * 4096 + (long)y * 64 + x;
      #pragma unroll 4
      for (int it = 0; it < 32; ++it) {
        int c = it * 4 + w;
        tile[c][x] = sp[(long)c * 262144];
      }
    }
    __syncthreads();
    if (in2 != nullptr) {
      #pragma unroll
      for (int it = 0; it < 4; ++it) {
        int chunk = it * 256 + t;
        int x = chunk >> 4, c8 = chunk & 15;
        short8 pk;
        #pragma unroll
        for (int j = 0; j < 8; ++j) pk[j] = (short)f2bf(tile[c8 * 8 + j][x]);
        *(short8*)(in2 + ((((long)(b * 64 + z) * 64 + y) * 64 + x) * 128 + c8 * 8)) = pk;
      }
    }
    {
      float s0 = 0.f, s1 = 0.f;
      #pragma unroll
      for (int px = 0; px < 16; ++px) s0 += tile[cc][(xh * 2) * 16 + px];
      #pragma unroll
      for (int px = 0; px < 16; ++px) s1 += tile[cc][(xh * 2 + 1) * 16 + px];
      part0 += s0; part1 += s1;
    }
    if (t < 64) {
      int s = inv[pz * 256 + y0 * 16 + (t & 15)];
      if (s >= 0) {
        int idx = atomicAdd(&mcnt, 1);
        mx[idx] = t;
        int n = zp * 16 + yp * 4 + (t >> 4);
        mrow[idx] = vox_row_base + (b * 64 + n) * 100 + s;
      }
    }
    __syncthreads();
    int mc = mcnt;
    for (int i = 0; i < mc; ++i) {
      if (t < 128) Xmat[(long)mrow[i] * 128 + t] = tile[t][mx[i]];
    }
  }
  long sb = ((long)(b * 64 + z) * 4 + yp) * 512;
  S4[sb + cc * 4 + xh * 2 + 0] = part0;
  S4[sb + cc * 4 + xh * 2 + 1] = part1;
}

// ---------------- conv: LDS-staged halo window + bf16 MFMA ----------------
// grid 2048 (XCD-swizzled): b(2) x z(64) x yg(16); 512 threads = 8 waves.
// wave = (xh = wave&1, yo = wave>>1): output tile 32x x 1y x 1z, 32 channels.
// LDS window: 18 rows (3z x 6y) x 64x x 64c bf16 = 144 KB, 2 channel-chunk passes.
// Row layout: [x][granule16B] with granule slot ^= (x&7) (attn-style swizzle, G4).
__global__ void __launch_bounds__(512) k_conv(const short* __restrict__ in2,
    const short* __restrict__ wt2, const float* __restrict__ c1b,
    const float* __restrict__ c2w, const float* __restrict__ c2b,
    int* __restrict__ counts) {
  extern __shared__ char smem[];
  __shared__ int lcnt[4];
  int bi0 = blockIdx.x;
  int bi = ((bi0 & 7) << 8) | (bi0 >> 3);          // bijective XCD swizzle (2048 = 8*256)
  int b = bi >> 10, z = (bi >> 4) & 63, yg = bi & 15;
  int y0 = yg * 4;
  int tid = threadIdx.x;
  int lane = tid & 63;
  int l31 = lane & 31, half = lane >> 5;
  int wave = tid >> 6;
  int xh = wave & 1, yo = wave >> 1;
  const short8 zer = {};

  if (tid < 4) lcnt[tid] = 0;

  // staging thread constants: granule g = tid (0..511): x = g>>3, kg = g&7
  int sx = tid >> 3, skg = tid & 7;
  int wofs = sx * 128 + ((skg ^ (sx & 7)) << 4);        // byte offset within LDS row
  int gofs = sx * 128 + skg * 8;                         // short offset within global row

  // A-fragment lane constants per dx (0..2 => dx-1) and ks
  int xbase = xh * 32 + l31;
  bool val[3];
  int offA[3][4];
  #pragma unroll
  for (int d = 0; d < 3; ++d) {
    int xp = xbase + d - 1;
    val[d] = (unsigned)xp < 64u;
    int xc = min(max(xp, 0), 63);
    #pragma unroll
    for (int ks = 0; ks < 4; ++ks) {
      int kg = ks * 2 + half;
      offA[d][ks] = xc * 128 + ((kg ^ (xc & 7)) << 4);
    }
  }

  f32x16 acc = {};

  for (int co = 0; co < 2; ++co) {
    __syncthreads();
    // ---- stage 18 halo rows of the 64-ch chunk ----
    #pragma unroll
    for (int wr = 0; wr < 18; ++wr) {
      int zz = z - 1 + wr / 6;
      int yy = y0 - 1 + wr % 6;
      short8 v = zer;
      if (((unsigned)zz < 64u) && ((unsigned)yy < 64u)) {
        long rowb = ((long)(b * 64 + zz) * 64 + yy) * 8192;
        v = *(const short8*)(in2 + rowb + gofs + co * 64);
      }
      *(short8*)(smem + wr * 8192 + wofs) = v;
    }
    __syncthreads();
    // ---- 27 taps x 4 k-steps ----
    for (int tap = 0; tap < 27; ++tap) {
      int dz = tap / 9;
      int r9 = tap - dz * 9;
      int dy = r9 / 3;
      int dxi = r9 - dy * 3;
      int slot = dz * 6 + yo + dy;                 // input row (z-1+dz, y0+yo-1+dy)
      const char* abase = smem + slot * 8192;
      const short8* pB = (const short8*)(wt2 + ((tap * 32 + l31) * 128 + co * 64 + half * 8));
      bool v = val[dxi];
      #pragma unroll
      for (int ks = 0; ks < 4; ++ks) {
        short8 bfr = pB[ks * 2];
        short8 afr = *(const short8*)(abase + offA[dxi][ks]);
        afr = v ? afr : zer;
        acc = __builtin_amdgcn_mfma_f32_32x32x16_bf16(afr, bfr, acc, 0, 0, 0);
      }
    }
  }

  // ---- epilogue: relu, 1x1, cross-lane ch-reduce, threshold, patch counts ----
  float b1v = c1b[l31];
  float w2v = c2w[l31];
  float b2v = c2b[0];
  int cnt0 = 0, cnt1 = 0;
  #pragma unroll
  for (int r = 0; r < 16; ++r) {
    float v = fmaxf(acc[r] + b1v, 0.f) * w2v;
    v += __shfl_xor(v, 1);
    v += __shfl_xor(v, 2);
    v += __shfl_xor(v, 4);
    v += __shfl_xor(v, 8);
    v += __shfl_xor(v, 16);
    int bit = (v + b2v) > THR_LOGIT;
    if (r < 8) cnt0 += bit; else cnt1 += bit;     // x-patch-local = r>>3
  }
  __syncthreads();
  if (l31 == 0) {                                  // lanes 0 and 32: distinct row sets
    atomicAdd(&lcnt[xh * 2 + 0], cnt0);
    atomicAdd(&lcnt[xh * 2 + 1], cnt1);
  }
  __syncthreads();
  if (tid < 4) {
    int n = (z >> 4) * 16 + (yg >> 2) * 4 + tid;
    atomicAdd(&counts[b * 64 + n], lcnt[tid]);
  }
}

// ---------------- reduce S4 -> X vec rows (deterministic) ----------------
__global__ void __launch_bounds__(256) k_vecreduce(const float* __restrict__ S4a,
    const float* __restrict__ S4p, float* __restrict__ Xmat) {
  int g = blockIdx.x * 256 + threadIdx.x;   // 32768
  int ten = g >> 14, rem = g & 16383;
  int b = rem >> 13, n = (rem >> 7) & 63, c = rem & 127;
  int zp = n >> 4, yp = (n >> 2) & 3, xp = n & 3;
  const float* S = ten ? S4p : S4a;
  float s = 0.f;
  #pragma unroll
  for (int k = 0; k < 16; ++k)
    s += S[((long)(b * 64 + zp * 16 + k) * 4 + yp) * 512 + c * 4 + xp];
  Xmat[(long)(ten * 128 + b * 64 + n) * 128 + c] = s * (1.f / 4096.f);
}

// ---------------- projector MLP + normalize ----------------
__global__ void __launch_bounds__(256) k_proj(const float* __restrict__ Xmat,
    const float* __restrict__ w1t, const float* __restrict__ pb1,
    const float* __restrict__ w2t, const float* __restrict__ pb2,
    float* __restrict__ P) {
  __shared__ float xsT[128][20];
  __shared__ float hsT[128][20];
  __shared__ float os[16][68];
  int bi = blockIdx.x;
  long row0 = (long)bi * 16;
  int t = threadIdx.x;
  {
    int r = t >> 4, c0 = (t & 15) * 8;
    const float* xp = Xmat + (row0 + r) * 128 + c0;
    #pragma unroll
    for (int k = 0; k < 8; ++k) xsT[c0 + k][r] = xp[k];
  }
  __syncthreads();
  {
    int j = t & 127, rh = t >> 7;
    float hacc[8];
    float bb = pb1[j];
    #pragma unroll
    for (int r8 = 0; r8 < 8; ++r8) hacc[r8] = bb;
    for (int c = 0; c < 128; ++c) {
      float w = w1t[c * 128 + j];
      float4 xlo = *(const float4*)&xsT[c][rh * 8];
      float4 xhi = *(const float4*)&xsT[c][rh * 8 + 4];
      hacc[0] += xlo.x * w; hacc[1] += xlo.y * w; hacc[2] += xlo.z * w; hacc[3] += xlo.w * w;
      hacc[4] += xhi.x * w; hacc[5] += xhi.y * w; hacc[6] += xhi.z * w; hacc[7] += xhi.w * w;
    }
    #pragma unroll
    for (int r8 = 0; r8 < 8; ++r8) hsT[j][rh * 8 + r8] = fmaxf(hacc[r8], 0.f);
  }
  __syncthreads();
  {
    int d = t & 63, rq = t >> 6;
    float oacc[4];
    float bb = pb2[d];
    #pragma unroll
    for (int r4 = 0; r4 < 4; ++r4) oacc[r4] = bb;
    for (int j = 0; j < 128; ++j) {
      float w = w2t[j * 64 + d];
      float4 hv = *(const float4*)&hsT[j][rq * 4];
      oacc[0] += hv.x * w; oacc[1] += hv.y * w; oacc[2] += hv.z * w; oacc[3] += hv.w * w;
    }
    #pragma unroll
    for (int r4 = 0; r4 < 4; ++r4) os[rq * 4 + r4][d] = oacc[r4];
  }
  __syncthreads();
  {
    int r = t >> 4, dg = t & 15;
    float4 v = *(const float4*)&os[r][dg * 4];
    float ss = v.x * v.x + v.y * v.y + v.z * v.z + v.w * v.w;
    ss += __shfl_xor(ss, 1); ss += __shfl_xor(ss, 2);
    ss += __shfl_xor(ss, 4); ss += __shfl_xor(ss, 8);
    float sc = 1.f / fmaxf(sqrtf(ss), 1e-12f);
    float4 o; o.x = v.x * sc; o.y = v.y * sc; o.z = v.z * sc; o.w = v.w * sc;
    *(float4*)&P[(row0 + r) * 64 + dg * 4] = o;
  }
}

// ---------------- sim + logsumexp per (b,n) ----------------
__global__ void __launch_bounds__(128) k_sim(const float* __restrict__ P,
                                             float* __restrict__ vloss) {
  __shared__ float ps[100][68];
  __shared__ float red[128];
  int bn = blockIdx.x;
  int t = threadIdx.x;
  long pbase = (long)(13056 + bn * 100) * 64;
  for (int i = t; i < 1600; i += 128) {
    int r = i >> 4, dg = i & 15;
    *(float4*)&ps[r][dg * 4] = *(const float4*)&P[pbase + r * 64 + dg * 4];
  }
  float4 areg[16];
  long abase = (long)(256 + bn * 100) * 64;
  if (t < 100) {
    #pragma unroll
    for (int j = 0; j < 16; ++j) areg[j] = *(const float4*)&P[abase + (long)t * 64 + j * 4];
  }
  __syncthreads();
  float res = 0.f;
  if (t < 100) {
    float m = -1e30f, sum = 0.f, diag = 0.f;
    for (int t2 = 0; t2 < 100; ++t2) {
      float d = 0.f;
      #pragma unroll
      for (int j = 0; j < 16; ++j) {
        float4 pv = *(const float4*)&ps[t2][j * 4];
        d += areg[j].x * pv.x + areg[j].y * pv.y + areg[j].z * pv.z + areg[j].w * pv.w;
      }
      float sim = d * 10.f;
      if (t2 == t) diag = sim;
      float nm = fmaxf(m, sim);
      sum = sum * __expf(m - nm) + __expf(sim - nm);
      m = nm;
    }
    res = m + logf(sum) - diag;
  }
  red[t] = res;
  __syncthreads();
  if (t == 0) {
    float s = 0.f;
    for (int i = 0; i < 100; ++i) s += red[i];
    vloss[bn] = s * 0.01f;
  }
}

// ---------------- final weighted reduction ----------------
__global__ void __launch_bounds__(128) k_final(const float* __restrict__ P,
    const float* __restrict__ vloss, const int* __restrict__ counts,
    const float* __restrict__ lw, float* __restrict__ out) {
  int t = threadIdx.x;
  int lane = t & 63;
  float pterm = 0.f, vterm = 0.f; int vcnt = 0;
  {
    int c = counts[t];
    bool maskv = c >= 2458;   // ratio > 0.6
    bool maskp = c <= 1638;   // ratio < 0.4
    float d = 0.f;
    for (int k = 0; k < 64; ++k) d += P[t * 64 + k] * P[(128 + t) * 64 + k];
    if (maskp) { pterm = -d * 10.f; vcnt += 1; }
    if (maskv) { vterm = vloss[t];  vcnt += 1; }
  }
  for (int m = 1; m < 64; m <<= 1) {
    pterm += __shfl_xor(pterm, m);
    vterm += __shfl_xor(vterm, m);
    vcnt  += __shfl_xor(vcnt, m);
  }
  __shared__ float sp[2], sv[2]; __shared__ int sc[2];
  if (lane == 0) { sp[t >> 6] = pterm; sv[t >> 6] = vterm; sc[t >> 6] = vcnt; }
  __syncthreads();
  if (t == 0) {
    float psum = sp[0] + sp[1], vsum = sv[0] + sv[1];
    int vc = sc[0] + sc[1];
    float total = lw[0] * psum + lw[1] * vsum;
    out[0] = (vc > 0) ? total / (float)vc : 0.f;
  }
}

// ---------------- launch ----------------
extern "C" void kernel_launch(void* const* d_in, const int* in_sizes, int n_in,
                              void* d_out, int out_size, void* d_ws, size_t ws_size,
                              hipStream_t stream) {
  const float* anchor   = (const float*)d_in[0];
  const float* positive = (const float*)d_in[1];
  const float* c1w = (const float*)d_in[2];
  const float* c1b = (const float*)d_in[3];
  const float* c2w = (const float*)d_in[4];
  const float* c2b = (const float*)d_in[5];
  const float* pw1 = (const float*)d_in[6];
  const float* pb1 = (const float*)d_in[7];
  const float* pw2 = (const float*)d_in[8];
  const float* pb2 = (const float*)d_in[9];
  const float* lw  = (const float*)d_in[10];
  const int*   vidx = (const int*)d_in[11];

  char* ws = (char*)d_ws;
  short* in2   = (short*)(ws + 0);                 // 134,217,728
  float* S4a   = (float*)(ws + 134217728);         // 1,048,576
  float* S4p   = (float*)(ws + 135266304);         // 1,048,576
  float* X     = (float*)(ws + 136314880);         // 13,238,272
  float* P     = (float*)(ws + 149553152);         // 6,619,136
  short* wt2   = (short*)(ws + 156172288);         // 221,184
  float* w1t   = (float*)(ws + 156393472);         // 65,536
  float* w2t   = (float*)(ws + 156459008);         // 32,768
  int*   inv   = (int*)  (ws + 156491776);         // 16,384
  int*   counts= (int*)  (ws + 156508160);         // 512
  float* vloss = (float*)(ws + 156508672);         // 512

  // allow >64KB dynamic LDS for k_conv (no-op if already permitted)
  hipFuncSetAttribute(reinterpret_cast<const void*>(k_conv),
                      hipFuncAttributeMaxDynamicSharedMemorySize, 147456);

  hipMemsetAsync(counts, 0, 128 * sizeof(int), stream);
  k_prep<<<528, 256, 0, stream>>>(c1w, pw1, pw2, wt2, w1t, w2t);
  k_inv<<<1, 256, 0, stream>>>(vidx, inv);
  k_stage<<<512, 256, 0, stream>>>(anchor,   in2,     S4a, X, inv, 256);
  k_stage<<<512, 256, 0, stream>>>(positive, nullptr, S4p, X, inv, 13056);
  k_conv<<<2048, 512, 147456, stream>>>(in2, wt2, c1b, c2w, c2b, counts);
  k_vecreduce<<<128, 256, 0, stream>>>(S4a, S4p, X);
  k_proj<<<1616, 256, 0, stream>>>(X, w1t, pb1, w2t, pb2, P);
  k_sim<<<128, 128, 0, stream>>>(P, vloss);
  k_final<<<1, 128, 0, stream>>>(P, vloss, counts, lw, (float*)d_out);
}

// Round 3
// 492.200 us; speedup vs baseline: 1.9131x; 1.4886x over previous
//
#include <hip/hip_runtime.h>

using short8 = __attribute__((ext_vector_type(8))) short;
using f32x16 = __attribute__((ext_vector_type(16))) float;

#define THR_LOGIT (-1.0986122886681098f)   // ln(1/3): sigmoid(x)>0.25 <=> x>ln(1/3)

__device__ __forceinline__ unsigned short f2bf(float f) {
  unsigned u = __float_as_uint(f);
  u = (u + 0x7FFFu + ((u >> 16) & 1u)) >> 16;   // RNE
  return (unsigned short)u;
}

// ---------------- prep: weight transposes ----------------
// wt2: [co(4)][tap(27)][ks(2)][half(2)][l31(32)][8c] bf16 (110592 shorts)
//   element: out-ch = l31, in-ch c = co*32 + ks*16 + half*8 + j8
__global__ void __launch_bounds__(256) k_prep(const float* __restrict__ c1w,
    const float* __restrict__ pw1, const float* __restrict__ pw2,
    short* __restrict__ wt2, float* __restrict__ w1t, float* __restrict__ w2t) {
  int i = blockIdx.x * 256 + threadIdx.x;
  if (i < 110592) {
    int j8 = i & 7, l31v = (i >> 3) & 31, halfv = (i >> 8) & 1, ksv = (i >> 9) & 1;
    int tapco = i >> 10;                 // 0..107
    int tap = tapco % 27, co = tapco / 27;
    int c = co * 32 + ksv * 16 + halfv * 8 + j8;
    wt2[i] = (short)f2bf(c1w[l31v * 3456 + c * 27 + tap]);
  } else if (i < 126976) {
    int i2 = i - 110592; int c = i2 >> 7; int j = i2 & 127;
    w1t[i2] = pw1[j * 128 + c];
  } else if (i < 135168) {
    int i3 = i - 126976; int j = i3 >> 6; int d = i3 & 63;
    w2t[i3] = pw2[d * 128 + j];
  }
}

__global__ void k_inv(const int* __restrict__ vidx, int* __restrict__ inv) {
  int t = threadIdx.x;
  for (int k = t; k < 4096; k += 256) inv[k] = -1;
  __syncthreads();
  if (t < 100) inv[vidx[t]] = t;
}

// ---------------- stage: transpose->bf16 [b][z][y][co][x][32c], patch sums, gather ----
__global__ void __launch_bounds__(256) k_stage(const float* __restrict__ src,
    short* __restrict__ in2, float* __restrict__ S4, float* __restrict__ Xmat,
    const int* __restrict__ inv, int vox_row_base) {
  __shared__ float tile[128][65];
  __shared__ int mcnt;
  __shared__ int mx[64];
  __shared__ int mrow[64];
  int bi = blockIdx.x;
  int b = bi >> 8, z = (bi >> 2) & 63, yp = bi & 3;
  int t = threadIdx.x;
  int zp = z >> 4, pz = z & 15;
  int cc = t & 127, xh = t >> 7;
  float part0 = 0.f, part1 = 0.f;

  for (int y0 = 0; y0 < 16; ++y0) {
    int y = yp * 16 + y0;
    __syncthreads();
    if (t == 0) mcnt = 0;
    {
      int x = t & 63, w = t >> 6;
      const float* sp = src + (long)b * 128 * 262144 + (long)z * 4096 + (long)y * 64 + x;
      #pragma unroll 4
      for (int it = 0; it < 32; ++it) {
        int c = it * 4 + w;
        tile[c][x] = sp[(long)c * 262144];
      }
    }
    __syncthreads();
    if (in2 != nullptr) {
      long rowbase = ((long)(b * 64 + z) * 64 + y) * 8192;
      #pragma unroll
      for (int it = 0; it < 4; ++it) {
        int chunk = it * 256 + t;
        int x = chunk >> 4, c8 = chunk & 15;
        short8 pk;
        #pragma unroll
        for (int j = 0; j < 8; ++j) pk[j] = (short)f2bf(tile[c8 * 8 + j][x]);
        *(short8*)(in2 + rowbase + (c8 >> 2) * 2048 + x * 32 + (c8 & 3) * 8) = pk;
      }
    }
    {
      float s0 = 0.f, s1 = 0.f;
      #pragma unroll
      for (int px = 0; px < 16; ++px) s0 += tile[cc][(xh * 2) * 16 + px];
      #pragma unroll
      for (int px = 0; px < 16; ++px) s1 += tile[cc][(xh * 2 + 1) * 16 + px];
      part0 += s0; part1 += s1;
    }
    if (t < 64) {
      int s = inv[pz * 256 + y0 * 16 + (t & 15)];
      if (s >= 0) {
        int idx = atomicAdd(&mcnt, 1);
        mx[idx] = t;
        int n = zp * 16 + yp * 4 + (t >> 4);
        mrow[idx] = vox_row_base + (b * 64 + n) * 100 + s;
      }
    }
    __syncthreads();
    int mc = mcnt;
    for (int i = 0; i < mc; ++i) {
      if (t < 128) Xmat[(long)mrow[i] * 128 + t] = tile[t][mx[i]];
    }
  }
  long sb = ((long)(b * 64 + z) * 4 + yp) * 512;
  S4[sb + cc * 4 + xh * 2 + 0] = part0;
  S4[sb + cc * 4 + xh * 2 + 1] = part1;
}

// ---------------- conv: LDS halo window (32-ch chunks) + bf16 MFMA ----------------
// grid 2048 (XCD-swizzled): b(2) x z(64) x yg(16); 512 threads = 8 waves.
// wave = (xh = wave&1, yo = wave>>1): output 32x x 1y x 1z, all 32 out-ch.
// 4 chunk passes of 32 in-ch. LDS window: 18 rows (3z x 6y) x 64x x 32c = 72 KB
//  -> 2 blocks/CU. Row layout: x*64B + ((kg ^ ((x>>1)&3))<<4): 8 lanes cover 32 banks.
__global__ void __launch_bounds__(512) k_conv(const short* __restrict__ in2,
    const short* __restrict__ wt2, const float* __restrict__ c1b,
    const float* __restrict__ c2w, const float* __restrict__ c2b,
    int* __restrict__ counts) {
  extern __shared__ char smem[];
  __shared__ int lcnt[4];
  int bi0 = blockIdx.x;
  int bi = ((bi0 & 7) << 8) | (bi0 >> 3);          // bijective XCD swizzle (2048 = 8*256)
  int b = bi >> 10, z = (bi >> 4) & 63, yg = bi & 15;
  int y0 = yg * 4;
  int tid = threadIdx.x;
  int lane = tid & 63;
  int l31 = lane & 31, half = lane >> 5;
  int wave = tid >> 6;
  int xh = wave & 1, yo = wave >> 1;
  const short8 zer = {};

  if (tid < 4) lcnt[tid] = 0;

  // staging: thread t handles granule g = t&255 of row-pair r2 = t>>8
  int sg = tid & 255, sr2 = tid >> 8;
  int sx = sg >> 2, skg = sg & 3;
  int wofs = sx * 64 + (((skg ^ ((sx >> 1) & 3))) << 4);   // LDS byte offset in row

  // A-fragment offsets per dx (0..2) and kg (ks*2+half)
  int xbase = xh * 32 + l31;
  bool val[3];
  int offA[3][2];
  #pragma unroll
  for (int d = 0; d < 3; ++d) {
    int xp = xbase + d - 1;
    val[d] = (unsigned)xp < 64u;
    int xc = min(max(xp, 0), 63);
    #pragma unroll
    for (int ks = 0; ks < 2; ++ks) {
      int kg = ks * 2 + half;
      offA[d][ks] = xc * 64 + ((kg ^ ((xc >> 1) & 3)) << 4);
    }
  }

  f32x16 acc0 = {}, acc1 = {};

  for (int co = 0; co < 4; ++co) {
    __syncthreads();
    // ---- stage 18 halo rows (contiguous 4KB each), 2 rows per iter ----
    #pragma unroll
    for (int it = 0; it < 9; ++it) {
      int wr = it * 2 + sr2;
      int zz = z - 1 + wr / 6;
      int yy = y0 - 1 + wr % 6;
      short8 v = zer;
      if (((unsigned)zz < 64u) && ((unsigned)yy < 64u)) {
        long rowb = (((long)(b * 64 + zz) * 64 + yy) * 4 + co) * 2048;
        v = *(const short8*)(in2 + rowb + sg * 8);
      }
      *(short8*)(smem + wr * 4096 + wofs) = v;
    }
    __syncthreads();
    // ---- 27 taps x 2 k-steps ----
    #pragma unroll
    for (int dz = 0; dz < 3; ++dz) {
      #pragma unroll
      for (int dy = 0; dy < 3; ++dy) {
        const char* abase = smem + (dz * 6 + yo + dy) * 4096;
        #pragma unroll
        for (int dxi = 0; dxi < 3; ++dxi) {
          int tap = dz * 9 + dy * 3 + dxi;
          const short8* pB = (const short8*)(wt2 +
              ((((co * 27 + tap) * 2 + 0) * 2 + half) * 32 + l31) * 8);
          bool v = val[dxi];
          short8 b0 = pB[0];
          short8 a0 = *(const short8*)(abase + offA[dxi][0]);
          a0 = v ? a0 : zer;
          acc0 = __builtin_amdgcn_mfma_f32_32x32x16_bf16(a0, b0, acc0, 0, 0, 0);
          short8 b1 = pB[8];   // ks=1: +2*32*8 shorts = +64 short8
          short8 a1 = *(const short8*)(abase + offA[dxi][1]);
          a1 = v ? a1 : zer;
          acc1 = __builtin_amdgcn_mfma_f32_32x32x16_bf16(a1, b1, acc1, 0, 0, 0);
        }
      }
    }
  }

  // ---- epilogue: relu, 1x1, cross-lane ch-reduce, threshold, patch counts ----
  float b1v = c1b[l31];
  float w2v = c2w[l31];
  float b2v = c2b[0];
  int cnt0 = 0, cnt1 = 0;
  #pragma unroll
  for (int r = 0; r < 16; ++r) {
    float v = fmaxf(acc0[r] + acc1[r] + b1v, 0.f) * w2v;
    v += __shfl_xor(v, 1);
    v += __shfl_xor(v, 2);
    v += __shfl_xor(v, 4);
    v += __shfl_xor(v, 8);
    v += __shfl_xor(v, 16);
    int bit = (v + b2v) > THR_LOGIT;
    if (r < 8) cnt0 += bit; else cnt1 += bit;
  }
  __syncthreads();
  if (l31 == 0) {
    atomicAdd(&lcnt[xh * 2 + 0], cnt0);
    atomicAdd(&lcnt[xh * 2 + 1], cnt1);
  }
  __syncthreads();
  if (tid < 4) {
    int n = (z >> 4) * 16 + (yg >> 2) * 4 + tid;
    atomicAdd(&counts[b * 64 + n], lcnt[tid]);
  }
}

// ---------------- reduce S4 -> X vec rows (deterministic) ----------------
__global__ void __launch_bounds__(256) k_vecreduce(const float* __restrict__ S4a,
    const float* __restrict__ S4p, float* __restrict__ Xmat) {
  int g = blockIdx.x * 256 + threadIdx.x;   // 32768
  int ten = g >> 14, rem = g & 16383;
  int b = rem >> 13, n = (rem >> 7) & 63, c = rem & 127;
  int zp = n >> 4, yp = (n >> 2) & 3, xp = n & 3;
  const float* S = ten ? S4p : S4a;
  float s = 0.f;
  #pragma unroll
  for (int k = 0; k < 16; ++k)
    s += S[((long)(b * 64 + zp * 16 + k) * 4 + yp) * 512 + c * 4 + xp];
  Xmat[(long)(ten * 128 + b * 64 + n) * 128 + c] = s * (1.f / 4096.f);
}

// ---------------- projector MLP + normalize ----------------
__global__ void __launch_bounds__(256) k_proj(const float* __restrict__ Xmat,
    const float* __restrict__ w1t, const float* __restrict__ pb1,
    const float* __restrict__ w2t, const float* __restrict__ pb2,
    float* __restrict__ P) {
  __shared__ float xsT[128][20];
  __shared__ float hsT[128][20];
  __shared__ float os[16][68];
  int bi = blockIdx.x;
  long row0 = (long)bi * 16;
  int t = threadIdx.x;
  {
    int r = t >> 4, c0 = (t & 15) * 8;
    const float* xp = Xmat + (row0 + r) * 128 + c0;
    #pragma unroll
    for (int k = 0; k < 8; ++k) xsT[c0 + k][r] = xp[k];
  }
  __syncthreads();
  {
    int j = t & 127, rh = t >> 7;
    float hacc[8];
    float bb = pb1[j];
    #pragma unroll
    for (int r8 = 0; r8 < 8; ++r8) hacc[r8] = bb;
    for (int c = 0; c < 128; ++c) {
      float w = w1t[c * 128 + j];
      float4 xlo = *(const float4*)&xsT[c][rh * 8];
      float4 xhi = *(const float4*)&xsT[c][rh * 8 + 4];
      hacc[0] += xlo.x * w; hacc[1] += xlo.y * w; hacc[2] += xlo.z * w; hacc[3] += xlo.w * w;
      hacc[4] += xhi.x * w; hacc[5] += xhi.y * w; hacc[6] += xhi.z * w; hacc[7] += xhi.w * w;
    }
    #pragma unroll
    for (int r8 = 0; r8 < 8; ++r8) hsT[j][rh * 8 + r8] = fmaxf(hacc[r8], 0.f);
  }
  __syncthreads();
  {
    int d = t & 63, rq = t >> 6;
    float oacc[4];
    float bb = pb2[d];
    #pragma unroll
    for (int r4 = 0; r4 < 4; ++r4) oacc[r4] = bb;
    for (int j = 0; j < 128; ++j) {
      float w = w2t[j * 64 + d];
      float4 hv = *(const float4*)&hsT[j][rq * 4];
      oacc[0] += hv.x * w; oacc[1] += hv.y * w; oacc[2] += hv.z * w; oacc[3] += hv.w * w;
    }
    #pragma unroll
    for (int r4 = 0; r4 < 4; ++r4) os[rq * 4 + r4][d] = oacc[r4];
  }
  __syncthreads();
  {
    int r = t >> 4, dg = t & 15;
    float4 v = *(const float4*)&os[r][dg * 4];
    float ss = v.x * v.x + v.y * v.y + v.z * v.z + v.w * v.w;
    ss += __shfl_xor(ss, 1); ss += __shfl_xor(ss, 2);
    ss += __shfl_xor(ss, 4); ss += __shfl_xor(ss, 8);
    float sc = 1.f / fmaxf(sqrtf(ss), 1e-12f);
    float4 o; o.x = v.x * sc; o.y = v.y * sc; o.z = v.z * sc; o.w = v.w * sc;
    *(float4*)&P[(row0 + r) * 64 + dg * 4] = o;
  }
}

// ---------------- sim + logsumexp per (b,n) ----------------
__global__ void __launch_bounds__(128) k_sim(const float* __restrict__ P,
                                             float* __restrict__ vloss) {
  __shared__ float ps[100][68];
  __shared__ float red[128];
  int bn = blockIdx.x;
  int t = threadIdx.x;
  long pbase = (long)(13056 + bn * 100) * 64;
  for (int i = t; i < 1600; i += 128) {
    int r = i >> 4, dg = i & 15;
    *(float4*)&ps[r][dg * 4] = *(const float4*)&P[pbase + r * 64 + dg * 4];
  }
  float4 areg[16];
  long abase = (long)(256 + bn * 100) * 64;
  if (t < 100) {
    #pragma unroll
    for (int j = 0; j < 16; ++j) areg[j] = *(const float4*)&P[abase + (long)t * 64 + j * 4];
  }
  __syncthreads();
  float res = 0.f;
  if (t < 100) {
    float m = -1e30f, sum = 0.f, diag = 0.f;
    for (int t2 = 0; t2 < 100; ++t2) {
      float d = 0.f;
      #pragma unroll
      for (int j = 0; j < 16; ++j) {
        float4 pv = *(const float4*)&ps[t2][j * 4];
        d += areg[j].x * pv.x + areg[j].y * pv.y + areg[j].z * pv.z + areg[j].w * pv.w;
      }
      float sim = d * 10.f;
      if (t2 == t) diag = sim;
      float nm = fmaxf(m, sim);
      sum = sum * __expf(m - nm) + __expf(sim - nm);
      m = nm;
    }
    res = m + logf(sum) - diag;
  }
  red[t] = res;
  __syncthreads();
  if (t == 0) {
    float s = 0.f;
    for (int i = 0; i < 100; ++i) s += red[i];
    vloss[bn] = s * 0.01f;
  }
}

// ---------------- final weighted reduction ----------------
__global__ void __launch_bounds__(128) k_final(const float* __restrict__ P,
    const float* __restrict__ vloss, const int* __restrict__ counts,
    const float* __restrict__ lw, float* __restrict__ out) {
  int t = threadIdx.x;
  int lane = t & 63;
  float pterm = 0.f, vterm = 0.f; int vcnt = 0;
  {
    int c = counts[t];
    bool maskv = c >= 2458;   // ratio > 0.6
    bool maskp = c <= 1638;   // ratio < 0.4
    float d = 0.f;
    for (int k = 0; k < 64; ++k) d += P[t * 64 + k] * P[(128 + t) * 64 + k];
    if (maskp) { pterm = -d * 10.f; vcnt += 1; }
    if (maskv) { vterm = vloss[t];  vcnt += 1; }
  }
  for (int m = 1; m < 64; m <<= 1) {
    pterm += __shfl_xor(pterm, m);
    vterm += __shfl_xor(vterm, m);
    vcnt  += __shfl_xor(vcnt, m);
  }
  __shared__ float sp[2], sv[2]; __shared__ int sc[2];
  if (lane == 0) { sp[t >> 6] = pterm; sv[t >> 6] = vterm; sc[t >> 6] = vcnt; }
  __syncthreads();
  if (t == 0) {
    float psum = sp[0] + sp[1], vsum = sv[0] + sv[1];
    int vc = sc[0] + sc[1];
    float total = lw[0] * psum + lw[1] * vsum;
    out[0] = (vc > 0) ? total / (float)vc : 0.f;
  }
}

// ---------------- launch ----------------
extern "C" void kernel_launch(void* const* d_in, const int* in_sizes, int n_in,
                              void* d_out, int out_size, void* d_ws, size_t ws_size,
                              hipStream_t stream) {
  const float* anchor   = (const float*)d_in[0];
  const float* positive = (const float*)d_in[1];
  const float* c1w = (const float*)d_in[2];
  const float* c1b = (const float*)d_in[3];
  const float* c2w = (const float*)d_in[4];
  const float* c2b = (const float*)d_in[5];
  const float* pw1 = (const float*)d_in[6];
  const float* pb1 = (const float*)d_in[7];
  const float* pw2 = (const float*)d_in[8];
  const float* pb2 = (const float*)d_in[9];
  const float* lw  = (const float*)d_in[10];
  const int*   vidx = (const int*)d_in[11];

  char* ws = (char*)d_ws;
  short* in2   = (short*)(ws + 0);                 // 134,217,728
  float* S4a   = (float*)(ws + 134217728);         // 1,048,576
  float* S4p   = (float*)(ws + 135266304);         // 1,048,576
  float* X     = (float*)(ws + 136314880);         // 13,238,272
  float* P     = (float*)(ws + 149553152);         // 6,619,136
  short* wt2   = (short*)(ws + 156172288);         // 221,184
  float* w1t   = (float*)(ws + 156393472);         // 65,536
  float* w2t   = (float*)(ws + 156459008);         // 32,768
  int*   inv   = (int*)  (ws + 156491776);         // 16,384
  int*   counts= (int*)  (ws + 156508160);         // 512
  float* vloss = (float*)(ws + 156508672);         // 512

  hipFuncSetAttribute(reinterpret_cast<const void*>(k_conv),
                      hipFuncAttributeMaxDynamicSharedMemorySize, 73728);

  hipMemsetAsync(counts, 0, 128 * sizeof(int), stream);
  k_prep<<<528, 256, 0, stream>>>(c1w, pw1, pw2, wt2, w1t, w2t);
  k_inv<<<1, 256, 0, stream>>>(vidx, inv);
  k_stage<<<512, 256, 0, stream>>>(anchor,   in2,     S4a, X, inv, 256);
  k_stage<<<512, 256, 0, stream>>>(positive, nullptr, S4p, X, inv, 13056);
  k_conv<<<2048, 512, 73728, stream>>>(in2, wt2, c1b, c2w, c2b, counts);
  k_vecreduce<<<128, 256, 0, stream>>>(S4a, S4p, X);
  k_proj<<<1616, 256, 0, stream>>>(X, w1t, pb1, w2t, pb2, P);
  k_sim<<<128, 128, 0, stream>>>(P, vloss);
  k_final<<<1, 128, 0, stream>>>(P, vloss, counts, lw, (float*)d_out);
}